// Round 8
// baseline (6807.193 us; speedup 1.0000x reference)
//
#include <hip/hip_runtime.h>
#include <stdint.h>

namespace {

constexpr int H   = 64;
constexpr int NIN = 21;
constexpr int T   = 3000;
constexpr int M   = 16;     // batch rows per block -> 32 blocks

typedef _Float16 f16x8 __attribute__((ext_vector_type(8)));
typedef float    f32x4 __attribute__((ext_vector_type(4)));

__device__ __forceinline__ float sigm(float v) { return 1.0f / (1.0f + __expf(-v)); }
__device__ __forceinline__ float tanh_fast(float v) {
    float e = __expf(2.0f * v);
    return 1.0f - 2.0f / (e + 1.0f);
}

// pack fp32 -> (f16 hi | f16 lo<<16); hi+lo reconstructs to ~2^-22 rel error
__device__ __forceinline__ uint32_t pack_hl(float f) {
    _Float16 hi = (_Float16)f;
    _Float16 lo = (_Float16)(f - (float)hi);
    return (uint32_t)__builtin_bit_cast(uint16_t, hi) |
           ((uint32_t)__builtin_bit_cast(uint16_t, lo) << 16);
}

__device__ __forceinline__ void unpack8(const uint32_t* pk, f16x8& hi, f16x8& lo) {
    #pragma unroll
    for (int j = 0; j < 8; ++j) {
        hi[j] = __builtin_bit_cast(_Float16, (uint16_t)(pk[j] & 0xffffu));
        lo[j] = __builtin_bit_cast(_Float16, (uint16_t)(pk[j] >> 16));
    }
}

__device__ __forceinline__ void cvt8(const float* s, f16x8& hi, f16x8& lo) {
    #pragma unroll
    for (int j = 0; j < 8; ++j) {
        float f = s[j];
        _Float16 h = (_Float16)f;
        hi[j] = h;
        lo[j] = (_Float16)(f - (float)h);
    }
}

#define MFMA(A, B, C) __builtin_amdgcn_mfma_f32_16x16x32_f16((A), (B), (C), 0, 0, 0)

// 8 waves: 0-3 layer0, 4-7 layer1. Wave w owns N-tiles at gate rows
// {16w+64q : q=0..3} so each lane holds i,f,g,o for (m,u) in-register.
// gates computed TRANSPOSED: D[n][m] = sum_k W[n][k] h[m][k] + bias[n].
//   A-frag (W): n_loc = lane&15, k = 32i + 8*(lane>>4) + j
//   B-frag (h): m     = lane&15, k = 32i + 8*(lane>>4) + j
//   D:          m = lane&15, n_loc = 4*(lane>>4) + v
__launch_bounds__(512, 1)
__global__ void lstm_mfma(const float* __restrict__ x,
                          const float* __restrict__ Wih0, const float* __restrict__ Whh0,
                          const float* __restrict__ bih0, const float* __restrict__ bhh0,
                          const float* __restrict__ Wih1, const float* __restrict__ Whh1,
                          const float* __restrict__ bih1, const float* __restrict__ bhh1,
                          const float* __restrict__ Wfc,  const float* __restrict__ bfc,
                          float* __restrict__ out)
{
    const int tid  = threadIdx.x;
    const int lane = tid & 63;
    const int wid  = tid >> 6;
    const int c    = lane >> 4;     // k-chunk (0..3)
    const int mc   = lane & 15;
    const int b0   = blockIdx.x * M;
    const bool isL0 = (wid < 4);
    const int  w    = wid & 3;

    // h exchanged as packed f16(hi,lo) u32; stride 65 -> <=2-way bank conflicts
    __shared__ uint32_t h1pk[16][65];
    __shared__ uint32_t h2pk[16][65];
    __shared__ uint32_t xpk[3][16][33];   // x staged 2 ahead, packed, zero-padded 21->32

    // ---------------- weight fragments (AGPR-friendly: only MFMA reads them) ----
    f16x8 wa_hi[4][2], wa_lo[4][2];   // L0: Whh0 | L1: Wih1   (A-operand, K=64)
    f16x8 wb_hi[4][2], wb_lo[4][2];   // L0: Wih0 in [q][0]    | L1: Whh1
    f32x4 bias[4];
    {
        const float* WA = isL0 ? Whh0 : Wih1;
        #pragma unroll
        for (int q = 0; q < 4; ++q) {
            const int n = 16 * w + 64 * q + mc;
            #pragma unroll
            for (int i = 0; i < 2; ++i) {
                float tmp[8];
                const float* p = WA + n * 64 + 32 * i + 8 * c;
                #pragma unroll
                for (int j = 0; j < 8; ++j) tmp[j] = p[j];
                cvt8(tmp, wa_hi[q][i], wa_lo[q][i]);
            }
            if (isL0) {
                float tmp[8];
                #pragma unroll
                for (int j = 0; j < 8; ++j) {
                    int k = 8 * c + j;
                    tmp[j] = (k < NIN) ? Wih0[n * NIN + k] : 0.0f;
                }
                cvt8(tmp, wb_hi[q][0], wb_lo[q][0]);
            } else {
                #pragma unroll
                for (int i = 0; i < 2; ++i) {
                    float tmp[8];
                    const float* p = Whh1 + n * 64 + 32 * i + 8 * c;
                    #pragma unroll
                    for (int j = 0; j < 8; ++j) tmp[j] = p[j];
                    cvt8(tmp, wb_hi[q][i], wb_lo[q][i]);
                }
            }
            const int nb = 16 * w + 64 * q + 4 * c;   // D-row index base
            #pragma unroll
            for (int v = 0; v < 4; ++v)
                bias[q][v] = isL0 ? (bih0[nb + v] + bhh0[nb + v])
                                  : (bih1[nb + v] + bhh1[nb + v]);
        }
    }

    // x staging role: 336 threads, one (row,feat) each
    const bool stg   = (tid < M * NIN);
    const int  srow  = stg ? (tid / NIN) : 0;
    const int  sfeat = stg ? (tid - srow * NIN) : 0;
    const float* xsrc = x + (size_t)(b0 + srow) * T * NIN + sfeat;

    // ---------------- LDS init ----------------
    for (int idx = tid; idx < 16 * 65; idx += 512) {
        (&h1pk[0][0])[idx] = 0u;
        (&h2pk[0][0])[idx] = 0u;
    }
    for (int idx = tid; idx < 3 * 16 * 33; idx += 512)
        (&xpk[0][0][0])[idx] = 0u;
    __syncthreads();                       // zero-fill before staging writes
    if (stg) {
        xpk[0][srow][sfeat] = pack_hl(xsrc[0]);
        xpk[1][srow][sfeat] = pack_hl(xsrc[NIN]);
    }

    f16x8 bh1_hi[2], bh1_lo[2], bh2_hi[2], bh2_lo[2];
    #pragma unroll
    for (int i = 0; i < 2; ++i)
        #pragma unroll
        for (int j = 0; j < 8; ++j) {
            bh1_hi[i][j] = (_Float16)0.0f; bh1_lo[i][j] = (_Float16)0.0f;
            bh2_hi[i][j] = (_Float16)0.0f; bh2_lo[i][j] = (_Float16)0.0f;
        }

    float cst[4] = {0.0f, 0.0f, 0.0f, 0.0f};
    int xcur = 0;
    __syncthreads();

    // Pipeline: iteration t computes layer0(t) and layer1(t-1).
    for (int t = 0; t <= T; ++t) {
        // issue next x load early (latency hidden under MFMAs)
        float xv = 0.0f;
        const bool do_stage = stg && (t + 2 < T);
        if (do_stage) xv = xsrc[(size_t)(t + 2) * NIN];

        // ---------------- phase A: MFMA + in-register pointwise ----------------
        if (isL0) {
            if (t < T) {
                f16x8 bx_hi, bx_lo;
                {
                    uint32_t pk[8];
                    #pragma unroll
                    for (int j = 0; j < 8; ++j) pk[j] = xpk[xcur][mc][8 * c + j];
                    unpack8(pk, bx_hi, bx_lo);
                }
                f32x4 acc[4];
                #pragma unroll
                for (int q = 0; q < 4; ++q) {
                    f32x4 a = bias[q];
                    a = MFMA(wb_hi[q][0], bx_hi, a);
                    a = MFMA(wb_lo[q][0], bx_hi, a);
                    a = MFMA(wb_hi[q][0], bx_lo, a);
                    #pragma unroll
                    for (int i = 0; i < 2; ++i) {
                        a = MFMA(wa_hi[q][i], bh1_hi[i], a);
                        a = MFMA(wa_lo[q][i], bh1_hi[i], a);
                        a = MFMA(wa_hi[q][i], bh1_lo[i], a);
                    }
                    acc[q] = a;
                }
                #pragma unroll
                for (int v = 0; v < 4; ++v) {
                    float i_ = sigm(acc[0][v]);
                    float f_ = sigm(acc[1][v]);
                    float g_ = tanh_fast(acc[2][v]);
                    float o_ = sigm(acc[3][v]);
                    cst[v] = fmaf(f_, cst[v], i_ * g_);
                    float h = o_ * tanh_fast(cst[v]);
                    h1pk[mc][16 * w + 4 * c + v] = pack_hl(h);
                }
            }
        } else {
            if (t > 0) {
                f32x4 acc[4];
                #pragma unroll
                for (int q = 0; q < 4; ++q) {
                    f32x4 a = bias[q];
                    #pragma unroll
                    for (int i = 0; i < 2; ++i) {
                        a = MFMA(wa_hi[q][i], bh1_hi[i], a);   // Wih1 * h1(t-1)
                        a = MFMA(wa_lo[q][i], bh1_hi[i], a);
                        a = MFMA(wa_hi[q][i], bh1_lo[i], a);
                        a = MFMA(wb_hi[q][i], bh2_hi[i], a);   // Whh1 * h2(t-2)
                        a = MFMA(wb_lo[q][i], bh2_hi[i], a);
                        a = MFMA(wb_hi[q][i], bh2_lo[i], a);
                    }
                    acc[q] = a;
                }
                #pragma unroll
                for (int v = 0; v < 4; ++v) {
                    float i_ = sigm(acc[0][v]);
                    float f_ = sigm(acc[1][v]);
                    float g_ = tanh_fast(acc[2][v]);
                    float o_ = sigm(acc[3][v]);
                    cst[v] = fmaf(f_, cst[v], i_ * g_);
                    float h = o_ * tanh_fast(cst[v]);
                    h2pk[mc][16 * w + 4 * c + v] = pack_hl(h);
                }
            }
        }
        if (do_stage) {
            int slot = xcur + 2; if (slot >= 3) slot -= 3;
            xpk[slot][srow][sfeat] = pack_hl(xv);
        }
        __syncthreads();   // h writes + x stage visible

        // ---------------- phase C: rebuild h B-fragments for next iteration ----
        if (t < T) {
            #pragma unroll
            for (int i = 0; i < 2; ++i) {
                uint32_t pk[8];
                #pragma unroll
                for (int j = 0; j < 8; ++j) pk[j] = h1pk[mc][32 * i + 8 * c + j];
                unpack8(pk, bh1_hi[i], bh1_lo[i]);
            }
            if (!isL0) {
                #pragma unroll
                for (int i = 0; i < 2; ++i) {
                    uint32_t pk[8];
                    #pragma unroll
                    for (int j = 0; j < 8; ++j) pk[j] = h2pk[mc][32 * i + 8 * c + j];
                    unpack8(pk, bh2_hi[i], bh2_lo[i]);
                }
            }
        }
        __syncthreads();   // frag reads done before next overwrite
        if (++xcur == 3) xcur = 0;
    }

    // ---------------- FC epilogue: out[b] = dot(h2, Wfc) + bfc ----------------
    #pragma unroll
    for (int v = 0; v < 2; ++v) {
        const int row = 2 * wid + v;
        uint32_t pk = h2pk[row][lane];
        float hv = (float)__builtin_bit_cast(_Float16, (uint16_t)(pk & 0xffffu))
                 + (float)__builtin_bit_cast(_Float16, (uint16_t)(pk >> 16));
        float val = hv * Wfc[lane];
        #pragma unroll
        for (int off = 32; off > 0; off >>= 1)
            val += __shfl_down(val, off, 64);
        if (lane == 0) out[b0 + row] = val + bfc[0];
    }
}

} // namespace

extern "C" void kernel_launch(void* const* d_in, const int* in_sizes, int n_in,
                              void* d_out, int out_size, void* d_ws, size_t ws_size,
                              hipStream_t stream)
{
    const float* x    = (const float*)d_in[0];
    const float* Wih0 = (const float*)d_in[1];
    const float* Whh0 = (const float*)d_in[2];
    const float* bih0 = (const float*)d_in[3];
    const float* bhh0 = (const float*)d_in[4];
    const float* Wih1 = (const float*)d_in[5];
    const float* Whh1 = (const float*)d_in[6];
    const float* bih1 = (const float*)d_in[7];
    const float* bhh1 = (const float*)d_in[8];
    const float* Wfc  = (const float*)d_in[9];
    const float* bfc  = (const float*)d_in[10];
    float* out = (float*)d_out;

    hipLaunchKernelGGL(lstm_mfma, dim3(512 / M), dim3(512), 0, stream,
                       x, Wih0, Whh0, bih0, bhh0, Wih1, Whh1, bih1, bhh1,
                       Wfc, bfc, out);
}

// Round 10
// 4177.793 us; speedup vs baseline: 1.6294x; 1.6294x over previous
//
#include <hip/hip_runtime.h>
#include <stdint.h>

namespace {

constexpr int NIN = 21;
constexpr int T   = 3000;
constexpr int NB  = 2;     // batches per block -> 256 blocks = 1 per CU

typedef _Float16 f16x8 __attribute__((ext_vector_type(8)));
typedef float    f32x4 __attribute__((ext_vector_type(4)));

__device__ __forceinline__ float sigm(float v){ return 1.0f/(1.0f+__expf(-v)); }
__device__ __forceinline__ float tanh_fast(float v){
    float e = __expf(2.0f*v);
    return 1.0f - 2.0f/(e + 1.0f);
}
__device__ __forceinline__ uint32_t pack_hl(float f){
    _Float16 hi = (_Float16)f;
    _Float16 lo = (_Float16)(f - (float)hi);
    return (uint32_t)__builtin_bit_cast(uint16_t, hi)
         | ((uint32_t)__builtin_bit_cast(uint16_t, lo) << 16);
}
__device__ __forceinline__ void cvt8(const float* s, f16x8& hi, f16x8& lo){
    #pragma unroll
    for (int j=0;j<8;++j){
        float f = s[j];
        _Float16 h = (_Float16)f;
        hi[j] = h;
        lo[j] = (_Float16)(f - (float)h);
    }
}
// build f16x8 from 8 packed (hi|lo<<16) u32; sh=0 -> hi halves, sh=16 -> lo halves
__device__ __forceinline__ f16x8 sel8(const uint32_t* pk, int sh){
    union { uint32_t u[4]; f16x8 v; } cv;
    #pragma unroll
    for (int p=0;p<4;++p){
        uint32_t a = pk[2*p]   >> sh;
        uint32_t b = pk[2*p+1] >> sh;
        cv.u[p] = (a & 0xffffu) | (b << 16);
    }
    return cv.v;
}
template<int CTRL>
__device__ __forceinline__ float dppf(float v){
    return __int_as_float(__builtin_amdgcn_update_dpp(
        0, __float_as_int(v), CTRL, 0xF, 0xF, true));
}
// Direction convention derived from the VERIFIED row_ror:J => out[i]=in[(i-J)&15]:
// rotate-right and shift-right move data the same way, so
//   row_ror:15 (0x12F) => out[i] = in[(i+1)&15]
//   row_shr:1  (0x111) => out[i] = in[i-1]        (round 9 wrongly used shl)
constexpr int ROR15 = 0x12F;
constexpr int SHR1  = 0x111;

#define MFMA(A,B,C) __builtin_amdgcn_mfma_f32_16x16x32_f16((A),(B),(C),0,0,0)

// Verified (round 8, passed 1.2e-7): D[n][m] = sum_k A[n][k]*B[m][k]
//   A-frag: n = lane&15, k(within 32-chunk) = 8*(lane>>4)+j
//   B-frag: m = lane&15, k = 8*(lane>>4)+j
//   D:      m = lane&15, n = 4*(lane>>4)+v
// B columns: m=0,1 = batch0 (hi,lo); m=2,3 = batch1 (hi,lo); m>=4 zero.
// One acc gets both A_hi and A_lo MFMAs; gate = D[.,2b] + D[.,2b+1]
//  = (whi+wlo)(hhi+hlo) = exact product to ~2^-22.
__launch_bounds__(512, 1)
__global__ void lstm_mf2(const float* __restrict__ x,
                         const float* __restrict__ Wih0, const float* __restrict__ Whh0,
                         const float* __restrict__ bih0, const float* __restrict__ bhh0,
                         const float* __restrict__ Wih1, const float* __restrict__ Whh1,
                         const float* __restrict__ bih1, const float* __restrict__ bhh1,
                         const float* __restrict__ Wfc,  const float* __restrict__ bfc,
                         float* __restrict__ out)
{
    const int tid  = threadIdx.x;
    const int lane = tid & 63;
    const int wid  = tid >> 6;
    const int c    = lane >> 4;     // k-subchunk 0..3
    const int mcol = lane & 15;     // D/B column
    const int b0   = blockIdx.x * NB;
    const bool isL0 = (wid < 4);
    const int  w    = wid & 3;      // layer-local wave -> u range [16w,16w+16)

    __shared__ uint32_t h1pk[2][NB][64];   // double-buffered packed h1
    __shared__ uint32_t h2pk[2][NB][64];
    __shared__ uint32_t xpk[4][NB][32];    // x staged 2 ahead, padded 21->32

    // ---------------- A fragments: [tile=gate][chunk] ----------------
    // L0 chunks: 0 = Wih0 (x, K=32 padded), 1,2 = Whh0.  L1: 0,1 = Wih1, 2,3 = Whh1.
    f16x8 Ahi[4][4], Alo[4][4];
    #pragma unroll
    for (int tau = 0; tau < 4; ++tau) {
        const int n = 64*tau + 16*w + mcol;
        float tmp[8];
        if (isL0) {
            #pragma unroll
            for (int j=0;j<8;++j){ int k = 8*c+j; tmp[j] = (k<NIN)? Wih0[n*NIN+k] : 0.0f; }
            cvt8(tmp, Ahi[tau][0], Alo[tau][0]);
            #pragma unroll
            for (int kc=0;kc<2;++kc){
                #pragma unroll
                for (int j=0;j<8;++j) tmp[j] = Whh0[n*64 + 32*kc + 8*c + j];
                cvt8(tmp, Ahi[tau][1+kc], Alo[tau][1+kc]);
            }
        } else {
            #pragma unroll
            for (int kc=0;kc<2;++kc){
                #pragma unroll
                for (int j=0;j<8;++j) tmp[j] = Wih1[n*64 + 32*kc + 8*c + j];
                cvt8(tmp, Ahi[tau][kc], Alo[tau][kc]);
            }
            #pragma unroll
            for (int kc=0;kc<2;++kc){
                #pragma unroll
                for (int j=0;j<8;++j) tmp[j] = Whh1[n*64 + 32*kc + 8*c + j];
                cvt8(tmp, Ahi[tau][2+kc], Alo[tau][2+kc]);
            }
        }
    }

    // biases for this lane's two pointwise units (valid when mcol<4)
    const int u0 = 16*w + 4*c + 2*(mcol & 1);
    float bI[2], bF[2], bG[2], bO[2];
    #pragma unroll
    for (int v=0; v<2; ++v){
        int u = u0 + v;
        if (isL0){
            bI[v]=bih0[u]+bhh0[u];       bF[v]=bih0[64+u]+bhh0[64+u];
            bG[v]=bih0[128+u]+bhh0[128+u]; bO[v]=bih0[192+u]+bhh0[192+u];
        } else {
            bI[v]=bih1[u]+bhh1[u];       bF[v]=bih1[64+u]+bhh1[64+u];
            bG[v]=bih1[128+u]+bhh1[128+u]; bO[v]=bih1[192+u]+bhh1[192+u];
        }
    }

    // ---------------- x staging (42 lanes, 4-deep prefetch) ----------------
    const bool stg = (tid < NB * NIN);
    const int  sb  = stg ? tid / NIN : 0;
    const int  sf  = stg ? tid - sb * NIN : 0;
    const float* xsrc = x + (size_t)(b0 + sb) * T * NIN + sf;

    // LDS zero init (h bufs + xpk incl pads)
    for (int i = tid; i < 2*NB*64; i += 512){ (&h1pk[0][0][0])[i]=0u; (&h2pk[0][0][0])[i]=0u; }
    for (int i = tid; i < 4*NB*32; i += 512) (&xpk[0][0][0])[i]=0u;
    __syncthreads();
    float xrA = 0.0f, xrB = 0.0f;
    if (stg){
        xpk[0][sb][sf] = pack_hl(xsrc[0]);
        xpk[1][sb][sf] = pack_hl(xsrc[(size_t)1*NIN]);
        xrA = xsrc[(size_t)2*NIN];
        xrB = xsrc[(size_t)3*NIN];
    }
    __syncthreads();

    // ---------------- B fragments for iteration t=0 ----------------
    f16x8 Bf[4];
    #pragma unroll
    for (int kc=0;kc<4;++kc)
        #pragma unroll
        for (int j=0;j<8;++j) Bf[kc][j] = (_Float16)0.0f;
    if (mcol < 4 && isL0){
        const int batch = mcol >> 1, sh = (mcol & 1) * 16;
        Bf[0] = sel8(&xpk[0][batch][8*c], sh);   // x(0); h frags stay 0
    }

    float cstA = 0.0f, cstB = 0.0f;   // c-state for this lane's 2 units

    // ================= main loop: iter t does layer0(t) and layer1(t-1) ======
    for (int t = 0; t <= T; ++t) {
        const bool run = isL0 ? (t < T) : (t > 0);
        if (run) {
            f32x4 acc[4];
            #pragma unroll
            for (int tau=0;tau<4;++tau) acc[tau] = (f32x4){0.f,0.f,0.f,0.f};
            if (isL0) {
                #pragma unroll
                for (int kc=0;kc<3;++kc){
                    #pragma unroll
                    for (int tau=0;tau<4;++tau) acc[tau] = MFMA(Ahi[tau][kc], Bf[kc], acc[tau]);
                    #pragma unroll
                    for (int tau=0;tau<4;++tau) acc[tau] = MFMA(Alo[tau][kc], Bf[kc], acc[tau]);
                }
            } else {
                #pragma unroll
                for (int kc=0;kc<4;++kc){
                    #pragma unroll
                    for (int tau=0;tau<4;++tau) acc[tau] = MFMA(Ahi[tau][kc], Bf[kc], acc[tau]);
                    #pragma unroll
                    for (int tau=0;tau<4;++tau) acc[tau] = MFMA(Alo[tau][kc], Bf[kc], acc[tau]);
                }
            }
            // combine cols m,m+1 (gate = hi-col + lo-col), then move rows {2,3}
            // results from even lanes to their odd neighbor (row_shr:1).
            float g0[4], g1[4];
            #pragma unroll
            for (int tau=0;tau<4;++tau){
                float c0 = acc[tau][0] + dppf<ROR15>(acc[tau][0]);
                float c1 = acc[tau][1] + dppf<ROR15>(acc[tau][1]);
                float c2 = acc[tau][2] + dppf<ROR15>(acc[tau][2]);
                float c3 = acc[tau][3] + dppf<ROR15>(acc[tau][3]);
                float s2 = dppf<SHR1>(c2);
                float s3 = dppf<SHR1>(c3);
                g0[tau] = (mcol & 1) ? s2 : c0;
                g1[tau] = (mcol & 1) ? s3 : c1;
            }
            if (mcol < 4) {
                const int batch = mcol >> 1;
                uint32_t (*dst)[64] = isL0 ? h1pk[t & 1] : h2pk[(t-1) & 1];
                float i_ = sigm(g0[0]+bI[0]), f_ = sigm(g0[1]+bF[0]);
                float gg = tanh_fast(g0[2]+bG[0]), o_ = sigm(g0[3]+bO[0]);
                cstA = fmaf(f_, cstA, i_*gg);
                dst[batch][u0]   = pack_hl(o_ * tanh_fast(cstA));
                i_ = sigm(g1[0]+bI[1]); f_ = sigm(g1[1]+bF[1]);
                gg = tanh_fast(g1[2]+bG[1]); o_ = sigm(g1[3]+bO[1]);
                cstB = fmaf(f_, cstB, i_*gg);
                dst[batch][u0+1] = pack_hl(o_ * tanh_fast(cstB));
            }
        }
        // x staging: write x(t+2) (loaded 2 iters ago), issue x(t+4)
        if (stg){
            if (t + 2 < T) xpk[(t+2) & 3][sb][sf] = pack_hl(xrA);
            xrA = xrB;
            if (t + 4 < T) xrB = xsrc[(size_t)(t+4) * NIN];
        }
        __syncthreads();

        // -------- build B fragments for iteration t+1 --------
        if (t < T && mcol < 4) {
            const int batch = mcol >> 1, sh = (mcol & 1) * 16;
            if (isL0) {
                Bf[0] = sel8(&xpk[(t+1) & 3][batch][8*c], sh);
                Bf[1] = sel8(&h1pk[t & 1][batch][8*c],      sh);
                Bf[2] = sel8(&h1pk[t & 1][batch][32 + 8*c], sh);
            } else {
                Bf[0] = sel8(&h1pk[t & 1][batch][8*c],        sh);
                Bf[1] = sel8(&h1pk[t & 1][batch][32 + 8*c],   sh);
                Bf[2] = sel8(&h2pk[(t+1) & 1][batch][8*c],      sh);  // h2(t-1)
                Bf[3] = sel8(&h2pk[(t+1) & 1][batch][32 + 8*c], sh);
            }
        }
        // no second barrier: all buffers double/quad-buffered
    }

    // ---------------- FC epilogue: out[b] = dot(h2(T-1), Wfc) + bfc ----------
    if (wid < NB) {
        uint32_t pk = h2pk[(T-1) & 1][wid][lane];
        float hv = (float)__builtin_bit_cast(_Float16, (uint16_t)(pk & 0xffffu))
                 + (float)__builtin_bit_cast(_Float16, (uint16_t)(pk >> 16));
        float val = hv * Wfc[lane];
        #pragma unroll
        for (int off = 32; off > 0; off >>= 1)
            val += __shfl_down(val, off, 64);
        if (lane == 0) out[b0 + wid] = val + bfc[0];
    }
}

} // namespace

extern "C" void kernel_launch(void* const* d_in, const int* in_sizes, int n_in,
                              void* d_out, int out_size, void* d_ws, size_t ws_size,
                              hipStream_t stream)
{
    const float* x    = (const float*)d_in[0];
    const float* Wih0 = (const float*)d_in[1];
    const float* Whh0 = (const float*)d_in[2];
    const float* bih0 = (const float*)d_in[3];
    const float* bhh0 = (const float*)d_in[4];
    const float* Wih1 = (const float*)d_in[5];
    const float* Whh1 = (const float*)d_in[6];
    const float* bih1 = (const float*)d_in[7];
    const float* bhh1 = (const float*)d_in[8];
    const float* Wfc  = (const float*)d_in[9];
    const float* bfc  = (const float*)d_in[10];
    float* out = (float*)d_out;

    hipLaunchKernelGGL(lstm_mf2, dim3(512 / NB), dim3(512), 0, stream,
                       x, Wih0, Whh0, bih0, bhh0, Wih1, Whh1, bih1, bhh1,
                       Wfc, bfc, out);
}

// Round 11
// 2842.706 us; speedup vs baseline: 2.3946x; 1.4697x over previous
//
#include <hip/hip_runtime.h>
#include <stdint.h>

namespace {

constexpr int NIN = 21;
constexpr int T   = 3000;
constexpr int NB  = 2;     // batches per block -> 256 blocks = 1 per CU

typedef _Float16 f16x8 __attribute__((ext_vector_type(8)));
typedef float    f32x4 __attribute__((ext_vector_type(4)));

__device__ __forceinline__ float frcp(float x){ return __builtin_amdgcn_rcpf(x); }
__device__ __forceinline__ float sigm(float v){ return frcp(1.0f + __expf(-v)); }
__device__ __forceinline__ float tanh_fast(float v){
    return fmaf(-2.0f, frcp(__expf(2.0f*v) + 1.0f), 1.0f);
}

template<int CTRL>
__device__ __forceinline__ float dppf(float v){
    return __int_as_float(__builtin_amdgcn_update_dpp(
        0, __float_as_int(v), CTRL, 0xF, 0xF, true));
}
// row_shr:N (0x110+N): out[i] = in[i-N] within 16-lane rows (verified r10 pass)
constexpr int SHR4  = 0x114;
constexpr int SHR8  = 0x118;
constexpr int SHR12 = 0x11C;

#define MFMA(A,B,C) __builtin_amdgcn_mfma_f32_16x16x32_f16((A),(B),(C),0,0,0)

__device__ __forceinline__ f16x8 ldfrag(const _Float16* p){
    return *reinterpret_cast<const f16x8*>(p);   // aligned 16B LDS read
}
__device__ __forceinline__ void cvt8v(const float* s, f16x8& hi, f16x8& lo){
    #pragma unroll
    for (int j=0;j<8;++j){
        float f = s[j];
        _Float16 h = (_Float16)f;
        hi[j] = h;
        lo[j] = (_Float16)(f - (float)h);
    }
}

// Verified MFMA layout (rounds 8/10): D[n][m] = sum_k A[n][k]*B[m][k]
//   A-frag: n = lane&15, k = 32*kc + 8*(lane>>4) + j
//   B-frag: m = lane&15, k = 32*kc + 8*(lane>>4) + j
//   D:      m = lane&15, n = 4*(lane>>4) + v
// Here B col m = batch m (m<2).  gate = bias + WhiHhi + WloHhi + WhiHlo.
__launch_bounds__(512, 2)
__global__ void lstm_mf3(const float* __restrict__ x,
                         const float* __restrict__ Wih0, const float* __restrict__ Whh0,
                         const float* __restrict__ bih0, const float* __restrict__ bhh0,
                         const float* __restrict__ Wih1, const float* __restrict__ Whh1,
                         const float* __restrict__ bih1, const float* __restrict__ bhh1,
                         const float* __restrict__ Wfc,  const float* __restrict__ bfc,
                         float* __restrict__ out)
{
    const int tid  = threadIdx.x;
    const int lane = tid & 63;
    const int wid  = tid >> 6;
    const int c    = lane >> 4;     // k-subchunk 0..3
    const int mcol = lane & 15;
    const int b0   = blockIdx.x * NB;
    const bool isL0 = (wid < 4);
    const int  w    = wid & 3;      // unit range [16w, 16w+16)

    // hi/lo f16 planes: frag rebuild = pure ds_read_b128
    __shared__ __align__(16) _Float16 h1p[2][2][NB][64]; // [buf][plane][batch][unit]
    __shared__ __align__(16) _Float16 h2p[2][2][NB][64];
    __shared__ __align__(16) _Float16 xp [4][2][NB][32]; // [slot][plane][batch][feat]

    // ----- weights: unified slots shared by roles (no union-liveness blowup) -----
    // L0: slot0 = Wih0 (K=32 padded), slot1,2 = Whh0, slot3 unused
    // L1: slot0,1 = Wih1, slot2,3 = Whh1
    f16x8 Whi[4][4], Wlo[4][4];
    f32x4 bias4[4];
    {
        float tmp[8];
        #pragma unroll
        for (int tau = 0; tau < 4; ++tau) {
            const int n = 64*tau + 16*w + mcol;
            if (isL0) {
                #pragma unroll
                for (int j=0;j<8;++j){ int k=8*c+j; tmp[j] = (k<NIN)? Wih0[n*NIN+k] : 0.0f; }
                cvt8v(tmp, Whi[tau][0], Wlo[tau][0]);
                #pragma unroll
                for (int kc=0;kc<2;++kc){
                    #pragma unroll
                    for (int j=0;j<8;++j) tmp[j] = Whh0[n*64 + 32*kc + 8*c + j];
                    cvt8v(tmp, Whi[tau][1+kc], Wlo[tau][1+kc]);
                }
            } else {
                #pragma unroll
                for (int kc=0;kc<2;++kc){
                    #pragma unroll
                    for (int j=0;j<8;++j) tmp[j] = Wih1[n*64 + 32*kc + 8*c + j];
                    cvt8v(tmp, Whi[tau][kc], Wlo[tau][kc]);
                }
                #pragma unroll
                for (int kc=0;kc<2;++kc){
                    #pragma unroll
                    for (int j=0;j<8;++j) tmp[j] = Whh1[n*64 + 32*kc + 8*c + j];
                    cvt8v(tmp, Whi[tau][2+kc], Wlo[tau][2+kc]);
                }
            }
            const int nb = 64*tau + 16*w + 4*c;
            #pragma unroll
            for (int v=0; v<4; ++v)
                bias4[tau][v] = isL0 ? (bih0[nb+v] + bhh0[nb+v])
                                     : (bih1[nb+v] + bhh1[nb+v]);
        }
    }

    // ----- LDS zero init -----
    {
        uint32_t* p1 = (uint32_t*)&h1p[0][0][0][0];
        uint32_t* p2 = (uint32_t*)&h2p[0][0][0][0];
        uint32_t* p3 = (uint32_t*)&xp[0][0][0][0];
        if (tid < 256){ p1[tid]=0u; p2[tid]=0u; p3[tid]=0u; }
    }
    __syncthreads();

    // ----- x staging: waves 0,1, lane<NIN -> (batch=wid, feat=lane) -----
    const bool stg = (wid < 2) && (lane < NIN);
    const float* xsrc = x + (size_t)(b0 + (wid & 1)) * T * NIN + lane;
    float xrA = 0.f, xrB = 0.f;
    if (stg){
        float x0 = xsrc[0], x1 = xsrc[NIN];
        _Float16 hh0 = (_Float16)x0;
        xp[0][0][wid][lane] = hh0;
        xp[0][1][wid][lane] = (_Float16)(x0 - (float)hh0);
        _Float16 hh1 = (_Float16)x1;
        xp[1][0][wid][lane] = hh1;
        xp[1][1][wid][lane] = (_Float16)(x1 - (float)hh1);
        xrA = xsrc[(size_t)2*NIN];
        xrB = xsrc[(size_t)3*NIN];
    }
    __syncthreads();

    // ----- B fragments (cols >=2 stay zero forever) -----
    f16x8 Bhi[4], Blo[4];
    #pragma unroll
    for (int kc=0;kc<4;++kc)
        #pragma unroll
        for (int j=0;j<8;++j){ Bhi[kc][j] = (_Float16)0.f; Blo[kc][j] = (_Float16)0.f; }
    if (isL0 && mcol < 2){
        Bhi[0] = ldfrag(&xp[0][0][mcol][8*c]);
        Blo[0] = ldfrag(&xp[0][1][mcol][8*c]);
        // h1(-1)=0: slots 1,2 stay zero
    }

    float cst = 0.f;   // c-state for this lane's (unit, batch)

    // ================= main loop: iter t = layer0(t) + layer1(t-1) ==========
    for (int t = 0; t <= T; ++t) {
        f32x4 a0 = bias4[0], a1 = bias4[1], a2 = bias4[2], a3 = bias4[3];
        #pragma unroll
        for (int kc=0; kc<4; ++kc){
            if (kc < 3 || !isL0) {     // wave-uniform: L0 has 3 chunks
                a0 = MFMA(Whi[0][kc], Bhi[kc], a0);
                a1 = MFMA(Whi[1][kc], Bhi[kc], a1);
                a2 = MFMA(Whi[2][kc], Bhi[kc], a2);
                a3 = MFMA(Whi[3][kc], Bhi[kc], a3);
                a0 = MFMA(Wlo[0][kc], Bhi[kc], a0);
                a1 = MFMA(Wlo[1][kc], Bhi[kc], a1);
                a2 = MFMA(Wlo[2][kc], Bhi[kc], a2);
                a3 = MFMA(Wlo[3][kc], Bhi[kc], a3);
                a0 = MFMA(Whi[0][kc], Blo[kc], a0);
                a1 = MFMA(Whi[1][kc], Blo[kc], a1);
                a2 = MFMA(Whi[2][kc], Blo[kc], a2);
                a3 = MFMA(Whi[3][kc], Blo[kc], a3);
            }
        }

        // spread D rows v=0..3 across lanes mcol = m + 4v (verified row_shr)
        const int q = mcol >> 2;
        float g0, g1, g2, g3;
        {
            float u1, u2, u3;
            u1 = dppf<SHR4>(a0[1]); u2 = dppf<SHR8>(a0[2]); u3 = dppf<SHR12>(a0[3]);
            g0 = (q==0)? a0[0] : (q==1)? u1 : (q==2)? u2 : u3;
            u1 = dppf<SHR4>(a1[1]); u2 = dppf<SHR8>(a1[2]); u3 = dppf<SHR12>(a1[3]);
            g1 = (q==0)? a1[0] : (q==1)? u1 : (q==2)? u2 : u3;
            u1 = dppf<SHR4>(a2[1]); u2 = dppf<SHR8>(a2[2]); u3 = dppf<SHR12>(a2[3]);
            g2 = (q==0)? a2[0] : (q==1)? u1 : (q==2)? u2 : u3;
            u1 = dppf<SHR4>(a3[1]); u2 = dppf<SHR8>(a3[2]); u3 = dppf<SHR12>(a3[3]);
            g3 = (q==0)? a3[0] : (q==1)? u1 : (q==2)? u2 : u3;
        }

        const bool run = isL0 ? (t < T) : (t > 0);
        if (run && (mcol & 2) == 0) {          // 32 lanes: 16 units x 2 batches
            const int m = mcol & 1;
            const int u = 16*w + 4*c + q;
            float i_ = sigm(g0), f_ = sigm(g1);
            float gg = tanh_fast(g2), o_ = sigm(g3);
            cst = fmaf(f_, cst, i_ * gg);
            float h = o_ * tanh_fast(cst);
            _Float16 hh = (_Float16)h;
            _Float16 hl = (_Float16)(h - (float)hh);
            _Float16* base = isL0 ? &h1p[t & 1][0][0][0] : &h2p[(t-1) & 1][0][0][0];
            base[m*64 + u]          = hh;      // hi plane
            base[NB*64 + m*64 + u]  = hl;      // lo plane
        }

        // x staging: write x(t+2) (fetched 2 iters ago), issue x(t+4)
        if (stg){
            if (t + 2 < T){
                _Float16 hh = (_Float16)xrA;
                xp[(t+2)&3][0][wid][lane] = hh;
                xp[(t+2)&3][1][wid][lane] = (_Float16)(xrA - (float)hh);
            }
            xrA = xrB;
            if (t + 4 < T) xrB = xsrc[(size_t)(t+4)*NIN];
        }
        __syncthreads();

        // -------- rebuild B fragments for iteration t+1 (pure b128 reads) ----
        if (t < T && mcol < 2){
            const int bt = mcol;
            const _Float16* h1b = &h1p[t & 1][0][0][0];
            if (isL0){
                Bhi[0] = ldfrag(&xp[(t+1)&3][0][bt][8*c]);
                Blo[0] = ldfrag(&xp[(t+1)&3][1][bt][8*c]);
                Bhi[1] = ldfrag(h1b + bt*64 + 8*c);
                Bhi[2] = ldfrag(h1b + bt*64 + 32 + 8*c);
                Blo[1] = ldfrag(h1b + NB*64 + bt*64 + 8*c);
                Blo[2] = ldfrag(h1b + NB*64 + bt*64 + 32 + 8*c);
            } else {
                const _Float16* h2b = &h2p[(t+1) & 1][0][0][0];   // h2(t-1)
                Bhi[0] = ldfrag(h1b + bt*64 + 8*c);
                Bhi[1] = ldfrag(h1b + bt*64 + 32 + 8*c);
                Blo[0] = ldfrag(h1b + NB*64 + bt*64 + 8*c);
                Blo[1] = ldfrag(h1b + NB*64 + bt*64 + 32 + 8*c);
                Bhi[2] = ldfrag(h2b + bt*64 + 8*c);
                Bhi[3] = ldfrag(h2b + bt*64 + 32 + 8*c);
                Blo[2] = ldfrag(h2b + NB*64 + bt*64 + 8*c);
                Blo[3] = ldfrag(h2b + NB*64 + bt*64 + 32 + 8*c);
            }
        }
        // single barrier/iter: all buffers double/quad-buffered (hazards checked)
    }

    // ---------------- FC epilogue: out[b] = dot(h2(T-1), Wfc) + bfc ----------
    if (wid < NB) {
        const _Float16* hb = &h2p[(T-1) & 1][0][0][0];
        float hv = (float)hb[wid*64 + lane] + (float)hb[NB*64 + wid*64 + lane];
        float val = hv * Wfc[lane];
        #pragma unroll
        for (int off = 32; off > 0; off >>= 1)
            val += __shfl_down(val, off, 64);
        if (lane == 0) out[b0 + wid] = val + bfc[0];
    }
}

} // namespace

extern "C" void kernel_launch(void* const* d_in, const int* in_sizes, int n_in,
                              void* d_out, int out_size, void* d_ws, size_t ws_size,
                              hipStream_t stream)
{
    const float* x    = (const float*)d_in[0];
    const float* Wih0 = (const float*)d_in[1];
    const float* Whh0 = (const float*)d_in[2];
    const float* bih0 = (const float*)d_in[3];
    const float* bhh0 = (const float*)d_in[4];
    const float* Wih1 = (const float*)d_in[5];
    const float* Whh1 = (const float*)d_in[6];
    const float* bih1 = (const float*)d_in[7];
    const float* bhh1 = (const float*)d_in[8];
    const float* Wfc  = (const float*)d_in[9];
    const float* bfc  = (const float*)d_in[10];
    float* out = (float*)d_out;

    hipLaunchKernelGGL(lstm_mf3, dim3(512 / NB), dim3(512), 0, stream,
                       x, Wih0, Whh0, bih0, bhh0, Wih1, Whh1, bih1, bhh1,
                       Wfc, bfc, out);
}

// Round 13
// 2522.392 us; speedup vs baseline: 2.6987x; 1.1270x over previous
//
#include <hip/hip_runtime.h>
#include <stdint.h>

namespace {

constexpr int NIN = 21;
constexpr int T   = 3000;
constexpr int NB  = 2;     // batches per block -> 256 blocks = 1 per CU

typedef _Float16 f16x8 __attribute__((ext_vector_type(8)));
typedef float    f32x4 __attribute__((ext_vector_type(4)));

__device__ __forceinline__ float frcp(float x){ return __builtin_amdgcn_rcpf(x); }
__device__ __forceinline__ float sigm(float v){ return frcp(1.0f + __expf(-v)); }
__device__ __forceinline__ float tanh_fast(float v){
    return fmaf(-2.0f, frcp(__expf(2.0f*v) + 1.0f), 1.0f);
}

template<int CTRL>
__device__ __forceinline__ float dppf(float v){
    return __int_as_float(__builtin_amdgcn_update_dpp(
        0, __float_as_int(v), CTRL, 0xF, 0xF, true));
}
// Verified family: row_ror:J => out[i] = in[(i-J)&15]; row_shr:N => out[i] = in[i-N]
constexpr int SHR4  = 0x114;
constexpr int SHR8  = 0x118;
constexpr int SHR12 = 0x11C;
constexpr int ROR14 = 0x12E;   // out[i] = in[(i+2)&15]

#define MFMA(A,B,C) __builtin_amdgcn_mfma_f32_16x16x32_f16((A),(B),(C),0,0,0)

__device__ __forceinline__ f16x8 ldfrag(const _Float16* p){
    return *reinterpret_cast<const f16x8*>(p);   // aligned 16B LDS read
}
__device__ __forceinline__ void cvt8v(const float* s, f16x8& hi, f16x8& lo){
    #pragma unroll
    for (int j=0;j<8;++j){
        float f = s[j];
        _Float16 h = (_Float16)f;
        hi[j] = h;
        lo[j] = (_Float16)(f - (float)h);
    }
}

// Verified MFMA layout (r8/r10/r11/r12-first-call): D[n][m] = sum_k A[n][k]*B[m][k]
//   A-frag: n = lane&15, k = 32*kc + 8*(lane>>4) + j
//   B-frag: m = lane&15, k = 32*kc + 8*(lane>>4) + j
//   D:      m = lane&15, n = 4*(lane>>4) + v
// B cols: 0,1 = batch0/1 Hhi; 2,3 = batch0/1 Hlo; >=4 zero.
// acc = MFMA(Whi,B) + MFMA(Wlo,B); gate = D[:,m] + D[:,m+2]
//     = (Whi+Wlo)(Hhi+Hlo)  -- all 4 hi/lo terms, exact to ~2^-22.
// Bias: halved in C-init (both summed columns carry it).
__launch_bounds__(512, 2)
__global__ void lstm_mf5(const float* __restrict__ x,
                         const float* __restrict__ Wih0, const float* __restrict__ Whh0,
                         const float* __restrict__ bih0, const float* __restrict__ bhh0,
                         const float* __restrict__ Wih1, const float* __restrict__ Whh1,
                         const float* __restrict__ bih1, const float* __restrict__ bhh1,
                         const float* __restrict__ Wfc,  const float* __restrict__ bfc,
                         float* __restrict__ out)
{
    const int tid  = threadIdx.x;
    const int lane = tid & 63;
    const int wid  = tid >> 6;
    const int c    = lane >> 4;     // k-subchunk 0..3
    const int mcol = lane & 15;
    const int b0   = blockIdx.x * NB;
    const bool isL0 = (wid < 4);
    const int  w    = wid & 3;      // unit range [16w, 16w+16)

    // hi/lo f16 planes, padded +8 (keeps 16B alignment, spreads banks)
    __shared__ __align__(16) _Float16 h1p[2][2][NB][72]; // [buf][plane][batch][unit(+pad)]
    __shared__ __align__(16) _Float16 h2p[2][2][NB][72];
    __shared__ __align__(16) _Float16 xp [4][2][NB][40]; // [slot][plane][batch][feat(+pad)]

    // ----- weights: unified slots shared by roles -----
    // L0: slot0 = Wih0 (K=32 padded), slot1,2 = Whh0, slot3 zero (unused)
    // L1: slot0,1 = Wih1, slot2,3 = Whh1
    f16x8 Whi[4][4], Wlo[4][4];
    f32x4 bias4[4];
    {
        float tmp[8];
        #pragma unroll
        for (int tau = 0; tau < 4; ++tau) {
            const int n = 64*tau + 16*w + mcol;
            if (isL0) {
                #pragma unroll
                for (int j=0;j<8;++j){ int k=8*c+j; tmp[j] = (k<NIN)? Wih0[n*NIN+k] : 0.0f; }
                cvt8v(tmp, Whi[tau][0], Wlo[tau][0]);
                #pragma unroll
                for (int kc=0;kc<2;++kc){
                    #pragma unroll
                    for (int j=0;j<8;++j) tmp[j] = Whh0[n*64 + 32*kc + 8*c + j];
                    cvt8v(tmp, Whi[tau][1+kc], Wlo[tau][1+kc]);
                }
                #pragma unroll
                for (int j=0;j<8;++j){ Whi[tau][3][j] = (_Float16)0.f; Wlo[tau][3][j] = (_Float16)0.f; }
            } else {
                #pragma unroll
                for (int kc=0;kc<2;++kc){
                    #pragma unroll
                    for (int j=0;j<8;++j) tmp[j] = Wih1[n*64 + 32*kc + 8*c + j];
                    cvt8v(tmp, Whi[tau][kc], Wlo[tau][kc]);
                }
                #pragma unroll
                for (int kc=0;kc<2;++kc){
                    #pragma unroll
                    for (int j=0;j<8;++j) tmp[j] = Whh1[n*64 + 32*kc + 8*c + j];
                    cvt8v(tmp, Whi[tau][2+kc], Wlo[tau][2+kc]);
                }
            }
            const int nb = 64*tau + 16*w + 4*c;
            #pragma unroll
            for (int v=0; v<4; ++v)
                bias4[tau][v] = 0.5f * (isL0 ? (bih0[nb+v] + bhh0[nb+v])
                                             : (bih1[nb+v] + bhh1[nb+v]));
        }
    }

    // ----- LDS zero init (full arrays incl. pads) -----
    {
        uint32_t* p1 = (uint32_t*)&h1p[0][0][0][0];   // 1152B = 288 u32
        uint32_t* p2 = (uint32_t*)&h2p[0][0][0][0];
        uint32_t* p3 = (uint32_t*)&xp[0][0][0][0];    // 1280B = 320 u32
        if (tid < 288){ p1[tid]=0u; p2[tid]=0u; }
        if (tid < 320){ p3[tid]=0u; }
    }
    __syncthreads();

    // ----- x staging: waves 0,1, lane<NIN -> (batch=wid, feat=lane) -----
    const bool stg = (wid < 2) && (lane < NIN);
    const float* xsrc = x + (size_t)(b0 + (wid & 1)) * T * NIN + lane;
    float xrA = 0.f, xrB = 0.f;
    if (stg){
        float x0 = xsrc[0], x1 = xsrc[NIN];
        _Float16 hh0 = (_Float16)x0;
        xp[0][0][wid][lane] = hh0;
        xp[0][1][wid][lane] = (_Float16)(x0 - (float)hh0);
        _Float16 hh1 = (_Float16)x1;
        xp[1][0][wid][lane] = hh1;
        xp[1][1][wid][lane] = (_Float16)(x1 - (float)hh1);
        xrA = xsrc[(size_t)2*NIN];
        xrB = xsrc[(size_t)3*NIN];
    }
    __syncthreads();

    // ----- B fragments: lane mcol<4 -> batch = mcol&1, plane = mcol>>1 -----
    f16x8 Bf[4];
    #pragma unroll
    for (int kc=0;kc<4;++kc)
        #pragma unroll
        for (int j=0;j<8;++j) Bf[kc][j] = (_Float16)0.f;
    if (isL0 && mcol < 4){
        Bf[0] = ldfrag(&xp[0][mcol>>1][mcol&1][8*c]);   // x(0); h slots stay 0
    }

    float cst = 0.f;   // c-state for this lane's (unit, batch)

    // ================= main loop: iter t = layer0(t) + layer1(t-1) ==========
    for (int t = 0; t <= T; ++t) {
        f32x4 a0 = bias4[0], a1 = bias4[1], a2 = bias4[2], a3 = bias4[3];
        #pragma unroll
        for (int kc=0; kc<4; ++kc){
            if (kc < 3 || !isL0) {     // wave-uniform: L0 has 3 chunks
                a0 = MFMA(Whi[0][kc], Bf[kc], a0);
                a1 = MFMA(Whi[1][kc], Bf[kc], a1);
                a2 = MFMA(Whi[2][kc], Bf[kc], a2);
                a3 = MFMA(Whi[3][kc], Bf[kc], a3);
                a0 = MFMA(Wlo[0][kc], Bf[kc], a0);
                a1 = MFMA(Wlo[1][kc], Bf[kc], a1);
                a2 = MFMA(Wlo[2][kc], Bf[kc], a2);
                a3 = MFMA(Wlo[3][kc], Bf[kc], a3);
            }
        }

        // spread D rows v=0..3 across lanes mcol = m' + 4v (verified row_shr),
        // then fold in cols m+2 (Hlo part) via row_ror:14 (lane i <- i+2).
        const int q = mcol >> 2;
        float g0, g1, g2, g3;
        {
            float u1, u2, u3;
            u1 = dppf<SHR4>(a0[1]); u2 = dppf<SHR8>(a0[2]); u3 = dppf<SHR12>(a0[3]);
            g0 = (q==0)? a0[0] : (q==1)? u1 : (q==2)? u2 : u3;
            u1 = dppf<SHR4>(a1[1]); u2 = dppf<SHR8>(a1[2]); u3 = dppf<SHR12>(a1[3]);
            g1 = (q==0)? a1[0] : (q==1)? u1 : (q==2)? u2 : u3;
            u1 = dppf<SHR4>(a2[1]); u2 = dppf<SHR8>(a2[2]); u3 = dppf<SHR12>(a2[3]);
            g2 = (q==0)? a2[0] : (q==1)? u1 : (q==2)? u2 : u3;
            u1 = dppf<SHR4>(a3[1]); u2 = dppf<SHR8>(a3[2]); u3 = dppf<SHR12>(a3[3]);
            g3 = (q==0)? a3[0] : (q==1)? u1 : (q==2)? u2 : u3;
            g0 += dppf<ROR14>(g0);
            g1 += dppf<ROR14>(g1);
            g2 += dppf<ROR14>(g2);
            g3 += dppf<ROR14>(g3);
        }

        const bool run = isL0 ? (t < T) : (t > 0);
        if (run && (mcol & 2) == 0) {          // 32 lanes: 16 units x 2 batches
            const int m = mcol & 1;
            const int u = 16*w + 4*c + q;
            float i_ = sigm(g0), f_ = sigm(g1);
            float gg = tanh_fast(g2), o_ = sigm(g3);
            cst = fmaf(f_, cst, i_ * gg);
            float h = o_ * tanh_fast(cst);
            _Float16 hh = (_Float16)h;
            _Float16 hl = (_Float16)(h - (float)hh);
            if (isL0){
                h1p[t & 1][0][m][u] = hh;
                h1p[t & 1][1][m][u] = hl;
            } else {
                h2p[(t-1) & 1][0][m][u] = hh;
                h2p[(t-1) & 1][1][m][u] = hl;
            }
        }

        // x staging: write x(t+2) (fetched 2 iters ago), issue x(t+4)
        if (stg){
            if (t + 2 < T){
                _Float16 hh = (_Float16)xrA;
                xp[(t+2)&3][0][wid][lane] = hh;
                xp[(t+2)&3][1][wid][lane] = (_Float16)(xrA - (float)hh);
            }
            xrA = xrB;
            if (t + 4 < T) xrB = xsrc[(size_t)(t+4)*NIN];
        }
        __syncthreads();

        // -------- rebuild B fragments for iteration t+1 (pure b128 reads) ----
        if (t < T && mcol < 4){
            const int bt = mcol & 1;
            const int p  = mcol >> 1;
            if (isL0){
                Bf[0] = ldfrag(&xp[(t+1)&3][p][bt][8*c]);
                Bf[1] = ldfrag(&h1p[t & 1][p][bt][8*c]);
                Bf[2] = ldfrag(&h1p[t & 1][p][bt][32 + 8*c]);
            } else {
                Bf[0] = ldfrag(&h1p[t & 1][p][bt][8*c]);
                Bf[1] = ldfrag(&h1p[t & 1][p][bt][32 + 8*c]);
                Bf[2] = ldfrag(&h2p[(t+1) & 1][p][bt][8*c]);        // h2(t-1)
                Bf[3] = ldfrag(&h2p[(t+1) & 1][p][bt][32 + 8*c]);
            }
        }
        // SECOND barrier: guarantees no rebuild-read overlaps the next
        // iteration's LDS writes regardless of wave drift (r12 post-timing
        // divergence — replay-only — is in this hazard class).
        __syncthreads();
    }

    // ---------------- FC epilogue: out[b] = dot(h2(T-1), Wfc) + bfc ----------
    if (wid < NB) {
        float hv = (float)h2p[(T-1) & 1][0][wid][lane]
                 + (float)h2p[(T-1) & 1][1][wid][lane];
        float val = hv * Wfc[lane];
        #pragma unroll
        for (int off = 32; off > 0; off >>= 1)
            val += __shfl_down(val, off, 64);
        if (lane == 0) out[b0 + wid] = val + bfc[0];
    }
}

} // namespace

extern "C" void kernel_launch(void* const* d_in, const int* in_sizes, int n_in,
                              void* d_out, int out_size, void* d_ws, size_t ws_size,
                              hipStream_t stream)
{
    const float* x    = (const float*)d_in[0];
    const float* Wih0 = (const float*)d_in[1];
    const float* Whh0 = (const float*)d_in[2];
    const float* bih0 = (const float*)d_in[3];
    const float* bhh0 = (const float*)d_in[4];
    const float* Wih1 = (const float*)d_in[5];
    const float* Whh1 = (const float*)d_in[6];
    const float* bih1 = (const float*)d_in[7];
    const float* bhh1 = (const float*)d_in[8];
    const float* Wfc  = (const float*)d_in[9];
    const float* bfc  = (const float*)d_in[10];
    float* out = (float*)d_out;

    hipLaunchKernelGGL(lstm_mf5, dim3(512 / NB), dim3(512), 0, stream,
                       x, Wih0, Whh0, bih0, bhh0, Wih1, Whh1, bih1, bhh1,
                       Wfc, bfc, out);
}